// Round 6
// baseline (90.450 us; speedup 1.0000x reference)
//
#include <hip/hip_runtime.h>

#define HW2   96
#define NH    12
#define LPIX  (HW2*HW2)      // 9216
#define BATCH 4

typedef __attribute__((ext_vector_type(8))) short bf16x8;
typedef __attribute__((ext_vector_type(4))) float f32x4;

static __device__ __forceinline__ float bf2f(unsigned short u) {
  union { unsigned int i; float f; } v; v.i = ((unsigned int)u) << 16; return v.f;
}
static __device__ __forceinline__ unsigned short f2bf(float f) {
  union { float f; unsigned int i; } v; v.f = f;
  unsigned int r = v.i + 0x7FFF + ((v.i >> 16) & 1);   // round-nearest-even
  return (unsigned short)(r >> 16);
}

// ---- tiny: convert the three weight matrices to bf16 ----------------------
__global__ __launch_bounds__(256) void cvt_w_kernel(
    const float* __restrict__ Wq, const float* __restrict__ Wkv,
    const float* __restrict__ Wp,
    unsigned short* __restrict__ wqb, unsigned short* __restrict__ wkvb,
    unsigned short* __restrict__ wpb) {
  int i = blockIdx.x * 256 + threadIdx.x;
  if (i < 9216)       wqb[i]          = f2bf(Wq[i]);
  else if (i < 27648) wkvb[i - 9216]  = f2bf(Wkv[i - 9216]);
  else if (i < 64512) wpb[i - 27648]  = f2bf(Wp[i - 27648]);
}

// ---- fused Q+KV GEMM; outputs HEAD-MAJOR: Qh[b][n][l][16],
//      KVh[b][n][l][K16|V16].  GEMM row r -> pixel l=r>>1, kv=r&1.
__global__ __launch_bounds__(256) void qkv_gemm(
    const float* __restrict__ X,
    const unsigned short* __restrict__ wq, const unsigned short* __restrict__ wkv,
    const float* __restrict__ bq, const float* __restrict__ bkv,
    const float* __restrict__ fqr, const float* __restrict__ fkr,
    const float* __restrict__ fvr,
    unsigned short* __restrict__ Qh, unsigned short* __restrict__ KVh)
{
  __shared__ unsigned short lds[19456];
  unsigned short* xs  = lds;            // stride 120
  unsigned short* qo  = lds;            // stride 104 (rows 64 x 96)
  unsigned short* kvo = lds + 6656;     // stride 200 (rows 64 x 192)

  const int tid = threadIdx.x;
  const int r0  = blockIdx.x * 64;
  const int b   = r0 / 18432;
  const int lb  = (r0 % 18432) >> 1;    // first pixel of this tile (32 pixels)

  const float4* xsrc = (const float4*)(X + (size_t)r0 * 96);
  #pragma unroll
  for (int it = 0; it < 6; it++) {
    int c = tid + it * 256;
    float4 v = xsrc[c];
    int row = c / 24, col = (c % 24) * 4;
    ushort4 p;
    p.x = f2bf(v.x); p.y = f2bf(v.y); p.z = f2bf(v.z); p.w = f2bf(v.w);
    *(ushort4*)&xs[row * 120 + col] = p;
  }
  __syncthreads();

  const int lane = tid & 63, w = tid >> 6;
  const int col  = lane & 15;
  const int koff = (lane >> 4) * 8;
  const int arow = 16 * w + (lane & 15);
  const int rloc = 16 * w + 4 * (lane >> 4);

  bf16x8 af0 = *(const bf16x8*)&xs[arow * 120 + koff];
  bf16x8 af1 = *(const bf16x8*)&xs[arow * 120 + koff + 32];
  bf16x8 af2 = *(const bf16x8*)&xs[arow * 120 + koff + 64];
  __syncthreads();                             // xs dead; reuse as qo/kvo

  const float fqr0 = fqr[0] * 0.07216878364870322f;
  const float fkr0 = fkr[0], fvr0 = fvr[0];

  #pragma unroll
  for (int nt = 0; nt < 18; nt++) {
    const unsigned short* wrow = (nt < 6)
        ? wq  + (size_t)(nt * 16 + col) * 96 + koff
        : wkv + (size_t)((nt - 6) * 16 + col) * 96 + koff;
    bf16x8 b0 = *(const bf16x8*)(wrow);
    bf16x8 b1 = *(const bf16x8*)(wrow + 32);
    bf16x8 b2 = *(const bf16x8*)(wrow + 64);
    f32x4 acc = {0.f, 0.f, 0.f, 0.f};
    acc = __builtin_amdgcn_mfma_f32_16x16x32_bf16(af0, b0, acc, 0, 0, 0);
    acc = __builtin_amdgcn_mfma_f32_16x16x32_bf16(af1, b1, acc, 0, 0, 0);
    acc = __builtin_amdgcn_mfma_f32_16x16x32_bf16(af2, b2, acc, 0, 0, 0);

    if (nt < 6) {
      int u = nt * 16 + col;
      float bias = bq[u];
      #pragma unroll
      for (int i = 0; i < 4; i++)
        qo[(rloc + i) * 104 + u] = f2bf((acc[i] + bias) * fqr0);
    } else {
      int u = (nt - 6) * 16 + col;
      float bias = bkv[u];
      #pragma unroll
      for (int i = 0; i < 4; i++) {
        float s = (i & 1) ? fvr0 : fkr0;       // row parity: even=K, odd=V
        kvo[(rloc + i) * 200 + u] = f2bf((acc[i] + bias) * s);
      }
    }
  }
  __syncthreads();

  // ---- head-major stores, fully-coalesced 16B runs per head region ----
  // Q: 768 chunks of 8 shorts: m -> n=m>>6, l_loc=(m&63)>>1, half=m&1
  #pragma unroll
  for (int it = 0; it < 3; it++) {
    int m = tid + it * 256;
    int n = m >> 6, rem = m & 63;
    int l_loc = rem >> 1, half = (m & 1) * 8;
    int srow = 2 * l_loc + (n >= 6);
    int scol = (n % 6) * 16 + half;
    unsigned short* dst = Qh + (size_t)b * 1769472 + (size_t)n * 147456
                        + (size_t)(lb + l_loc) * 16 + half;
    *(uint4*)dst = *(const uint4*)&qo[srow * 104 + scol];
  }
  // KV: 1536 chunks: m -> n=m>>7, l_loc=(m&127)>>2, kv=(m>>1)&1, half=m&1
  #pragma unroll
  for (int it = 0; it < 6; it++) {
    int m = tid + it * 256;
    int n = m >> 7, rem = m & 127;
    int l_loc = rem >> 2;
    int kv = (m >> 1) & 1, half = (m & 1) * 8;
    int srow = 2 * l_loc + kv;
    int scol = n * 16 + half;
    unsigned short* dst = KVh + (size_t)b * 3538944 + (size_t)n * 294912
                        + (size_t)(lb + l_loc) * 32 + kv * 16 + half;
    *(uint4*)dst = *(const uint4*)&kvo[srow * 200 + scol];
  }
}

// ---- fused attention + proj: block = 32 pixels x 12 heads, 384 threads ----
// thread = (n = tid>>5, pl = tid&31): per neighbor, each 32-lane group reads
// 32 consecutive 64B pixel blocks -> 2KB contiguous (coalesced by layout).
__global__ __launch_bounds__(384) void attnproj_kernel(
    const unsigned short* __restrict__ Qh, const unsigned short* __restrict__ KVh,
    const unsigned short* __restrict__ wp, const float* __restrict__ bp,
    float* __restrict__ Out)
{
  __shared__ unsigned short s_out[32 * 204];
  const int tid = threadIdx.x;
  const int bl0 = blockIdx.x * 32;

  {
    const int n  = tid >> 5;                   // 0..11
    const int pl = tid & 31;                   // 0..31
    const int bl = bl0 + pl;
    const int l  = bl % LPIX;
    const int b  = bl / LPIX;
    const int h2 = l / HW2, w2 = l - h2 * HW2;

    const unsigned short* qp = Qh + (size_t)b * 1769472 + (size_t)n * 147456
                             + (size_t)l * 16;
    uint4 qA = *(const uint4*)(qp);
    uint4 qB = *(const uint4*)(qp + 8);

    const unsigned short* kvb = KVh + (size_t)b * 3538944 + (size_t)n * 294912;

    int  nbo[9];
    bool okk[9];
    uint4 kA[9], kB[9];
    #pragma unroll
    for (int kk = 0; kk < 9; kk++) {
      int hh = h2 + kk / 3 - 1;
      int ww = w2 + kk % 3 - 1;
      okk[kk] = ((unsigned)hh < (unsigned)HW2) && ((unsigned)ww < (unsigned)HW2);
      int hc = min(max(hh, 0), HW2 - 1);
      int wc = min(max(ww, 0), HW2 - 1);
      nbo[kk] = (hc * HW2 + wc) * 32;
      const unsigned short* kp = kvb + nbo[kk];
      kA[kk] = *(const uint4*)(kp);
      kB[kk] = *(const uint4*)(kp + 8);
    }

    float q[16];
    {
      const unsigned short* qs = (const unsigned short*)&qA;
      #pragma unroll
      for (int j = 0; j < 8; j++) q[j] = bf2f(qs[j]);
      qs = (const unsigned short*)&qB;
      #pragma unroll
      for (int j = 0; j < 8; j++) q[8 + j] = bf2f(qs[j]);
    }

    float sc[9];
    #pragma unroll
    for (int kk = 0; kk < 9; kk++) {
      float s = 0.f;
      const unsigned short* kd = (const unsigned short*)&kA[kk];
      #pragma unroll
      for (int j = 0; j < 8; j++) s = fmaf(q[j], bf2f(kd[j]), s);
      kd = (const unsigned short*)&kB[kk];
      #pragma unroll
      for (int j = 0; j < 8; j++) s = fmaf(q[8 + j], bf2f(kd[j]), s);
      sc[kk] = okk[kk] ? s : 0.f;
    }

    uint4 vA[9], vB[9];
    #pragma unroll
    for (int kk = 0; kk < 9; kk++) {
      const unsigned short* vp = kvb + nbo[kk] + 16;
      vA[kk] = *(const uint4*)(vp);
      vB[kk] = *(const uint4*)(vp + 8);
    }

    float m = sc[0];
    #pragma unroll
    for (int kk = 1; kk < 9; kk++) m = fmaxf(m, sc[kk]);
    float ssum = 0.f;
    #pragma unroll
    for (int kk = 0; kk < 9; kk++) {
      float e = __expf(sc[kk] - m);
      sc[kk] = e;
      ssum += e;
    }

    float acc[16];
    #pragma unroll
    for (int j = 0; j < 16; j++) acc[j] = 0.f;
    #pragma unroll
    for (int kk = 0; kk < 9; kk++) {
      float wgt = okk[kk] ? sc[kk] : 0.f;
      const unsigned short* vd = (const unsigned short*)&vA[kk];
      #pragma unroll
      for (int j = 0; j < 8; j++) acc[j] = fmaf(wgt, bf2f(vd[j]), acc[j]);
      vd = (const unsigned short*)&vB[kk];
      #pragma unroll
      for (int j = 0; j < 8; j++) acc[8 + j] = fmaf(wgt, bf2f(vd[j]), acc[8 + j]);
    }
    float rinv = 1.f / ssum;
    unsigned short od[16];
    #pragma unroll
    for (int j = 0; j < 16; j++) od[j] = f2bf(acc[j] * rinv);
    unsigned short* op = s_out + pl * 204 + n * 16;
    *(uint4*)(op)     = *(uint4*)&od[0];
    *(uint4*)(op + 8) = *(uint4*)&od[8];
  }
  __syncthreads();

  // ---- proj phase: (32x192 bf16 LDS) x Wp^T + bp -> Out fp32, 6 waves ----
  const int lane = tid & 63, w = tid >> 6;     // 6 waves
  const int wr = w & 1, wh = w >> 1;           // wr: row half, wh: 0..2
  const int col  = lane & 15;
  const int koff = (lane >> 4) * 8;
  const int arow = 16 * wr + (lane & 15);
  const int rbase = bl0 + 16 * wr + 4 * (lane >> 4);

  bf16x8 af[6];
  #pragma unroll
  for (int kt = 0; kt < 6; kt++)
    af[kt] = *(const bf16x8*)&s_out[arow * 204 + koff + kt * 32];

  #pragma unroll
  for (int t4 = 0; t4 < 4; t4++) {
    int nt = wh * 4 + t4;
    const unsigned short* wrow = wp + (size_t)(nt * 16 + col) * 192 + koff;
    f32x4 acc = {0.f, 0.f, 0.f, 0.f};
    #pragma unroll
    for (int kt = 0; kt < 6; kt++) {
      bf16x8 bfr = *(const bf16x8*)(wrow + kt * 32);
      acc = __builtin_amdgcn_mfma_f32_16x16x32_bf16(af[kt], bfr, acc, 0, 0, 0);
    }
    int u = nt * 16 + col;
    float bias = bp[u];
    #pragma unroll
    for (int i = 0; i < 4; i++)
      Out[(size_t)(rbase + i) * 192 + u] = acc[i] + bias;
  }
}

extern "C" void kernel_launch(void* const* d_in, const int* in_sizes, int n_in,
                              void* d_out, int out_size, void* d_ws, size_t ws_size,
                              hipStream_t stream) {
  const float* x   = (const float*)d_in[0];
  const float* Wq  = (const float*)d_in[1];
  const float* bq  = (const float*)d_in[2];
  const float* Wkv = (const float*)d_in[3];
  const float* bkv = (const float*)d_in[4];
  const float* Wp  = (const float*)d_in[5];
  const float* bp  = (const float*)d_in[6];
  const float* fqr = (const float*)d_in[7];
  const float* fkr = (const float*)d_in[8];
  const float* fvr = (const float*)d_in[9];

  char* ws = (char*)d_ws;
  unsigned short* Qh   = (unsigned short*)ws;                 // 14,155,776 B
  unsigned short* KVh  = (unsigned short*)(ws + 14155776);    // 28,311,552 B
  unsigned short* wqb  = (unsigned short*)(ws + 42467328);
  unsigned short* wkvb = (unsigned short*)(ws + 42485760);
  unsigned short* wpb  = (unsigned short*)(ws + 42522624);

  cvt_w_kernel<<<dim3(252), dim3(256), 0, stream>>>(Wq, Wkv, Wp, wqb, wkvb, wpb);

  qkv_gemm<<<dim3(1152), dim3(256), 0, stream>>>(
      x, wqb, wkvb, bq, bkv, fqr, fkr, fvr, Qh, KVh);

  attnproj_kernel<<<dim3(1152), dim3(384), 0, stream>>>(
      Qh, KVh, wpb, bp, (float*)d_out);
}

// Round 7
// 90.240 us; speedup vs baseline: 1.0023x; 1.0023x over previous
//
#include <hip/hip_runtime.h>

#define HW2   96
#define NH    12
#define LPIX  (HW2*HW2)      // 9216
#define BATCH 4

typedef __attribute__((ext_vector_type(8))) short bf16x8;
typedef __attribute__((ext_vector_type(4))) float f32x4;

static __device__ __forceinline__ float bf2f(unsigned short u) {
  union { unsigned int i; float f; } v; v.i = ((unsigned int)u) << 16; return v.f;
}
static __device__ __forceinline__ unsigned short f2bf(float f) {
  union { float f; unsigned int i; } v; v.f = f;
  unsigned int r = v.i + 0x7FFF + ((v.i >> 16) & 1);   // round-nearest-even
  return (unsigned short)(r >> 16);
}

// ---- tiny: convert the three weight matrices to bf16 ----------------------
__global__ __launch_bounds__(256) void cvt_w_kernel(
    const float* __restrict__ Wq, const float* __restrict__ Wkv,
    const float* __restrict__ Wp,
    unsigned short* __restrict__ wqb, unsigned short* __restrict__ wkvb,
    unsigned short* __restrict__ wpb) {
  int i = blockIdx.x * 256 + threadIdx.x;
  if (i < 9216)       wqb[i]          = f2bf(Wq[i]);
  else if (i < 27648) wkvb[i - 9216]  = f2bf(Wkv[i - 9216]);
  else if (i < 64512) wpb[i - 27648]  = f2bf(Wp[i - 27648]);
}

// ---- fused Q+KV GEMM; outputs HEAD-MAJOR: Qh[b][n][l][16],
//      KVh[b][n][l][K16|V16].  GEMM row r -> pixel l=r>>1, kv=r&1.
__global__ __launch_bounds__(256) void qkv_gemm(
    const float* __restrict__ X,
    const unsigned short* __restrict__ wq, const unsigned short* __restrict__ wkv,
    const float* __restrict__ bq, const float* __restrict__ bkv,
    const float* __restrict__ fqr, const float* __restrict__ fkr,
    const float* __restrict__ fvr,
    unsigned short* __restrict__ Qh, unsigned short* __restrict__ KVh)
{
  __shared__ unsigned short lds[19456];
  unsigned short* xs  = lds;            // stride 120
  unsigned short* qo  = lds;            // stride 104 (rows 64 x 96)
  unsigned short* kvo = lds + 6656;     // stride 200 (rows 64 x 192)

  const int tid = threadIdx.x;
  const int r0  = blockIdx.x * 64;
  const int b   = r0 / 18432;
  const int lb  = (r0 % 18432) >> 1;    // first pixel of this tile (32 pixels)

  const float4* xsrc = (const float4*)(X + (size_t)r0 * 96);
  #pragma unroll
  for (int it = 0; it < 6; it++) {
    int c = tid + it * 256;
    float4 v = xsrc[c];
    int row = c / 24, col = (c % 24) * 4;
    ushort4 p;
    p.x = f2bf(v.x); p.y = f2bf(v.y); p.z = f2bf(v.z); p.w = f2bf(v.w);
    *(ushort4*)&xs[row * 120 + col] = p;
  }
  __syncthreads();

  const int lane = tid & 63, w = tid >> 6;
  const int col  = lane & 15;
  const int koff = (lane >> 4) * 8;
  const int arow = 16 * w + (lane & 15);
  const int rloc = 16 * w + 4 * (lane >> 4);

  bf16x8 af0 = *(const bf16x8*)&xs[arow * 120 + koff];
  bf16x8 af1 = *(const bf16x8*)&xs[arow * 120 + koff + 32];
  bf16x8 af2 = *(const bf16x8*)&xs[arow * 120 + koff + 64];
  __syncthreads();                             // xs dead; reuse as qo/kvo

  const float fqr0 = fqr[0] * 0.07216878364870322f;
  const float fkr0 = fkr[0], fvr0 = fvr[0];

  #pragma unroll
  for (int nt = 0; nt < 18; nt++) {
    const unsigned short* wrow = (nt < 6)
        ? wq  + (size_t)(nt * 16 + col) * 96 + koff
        : wkv + (size_t)((nt - 6) * 16 + col) * 96 + koff;
    bf16x8 b0 = *(const bf16x8*)(wrow);
    bf16x8 b1 = *(const bf16x8*)(wrow + 32);
    bf16x8 b2 = *(const bf16x8*)(wrow + 64);
    f32x4 acc = {0.f, 0.f, 0.f, 0.f};
    acc = __builtin_amdgcn_mfma_f32_16x16x32_bf16(af0, b0, acc, 0, 0, 0);
    acc = __builtin_amdgcn_mfma_f32_16x16x32_bf16(af1, b1, acc, 0, 0, 0);
    acc = __builtin_amdgcn_mfma_f32_16x16x32_bf16(af2, b2, acc, 0, 0, 0);

    if (nt < 6) {
      int u = nt * 16 + col;
      float bias = bq[u];
      #pragma unroll
      for (int i = 0; i < 4; i++)
        qo[(rloc + i) * 104 + u] = f2bf((acc[i] + bias) * fqr0);
    } else {
      int u = (nt - 6) * 16 + col;
      float bias = bkv[u];
      #pragma unroll
      for (int i = 0; i < 4; i++) {
        float s = (i & 1) ? fvr0 : fkr0;       // row parity: even=K, odd=V
        kvo[(rloc + i) * 200 + u] = f2bf((acc[i] + bias) * s);
      }
    }
  }
  __syncthreads();

  // ---- head-major stores, fully-coalesced 16B runs per head region ----
  // Q: 768 chunks of 8 shorts: m -> n=m>>6, l_loc=(m&63)>>1, half=m&1
  #pragma unroll
  for (int it = 0; it < 3; it++) {
    int m = tid + it * 256;
    int n = m >> 6, rem = m & 63;
    int l_loc = rem >> 1, half = (m & 1) * 8;
    int srow = 2 * l_loc + (n >= 6);
    int scol = (n % 6) * 16 + half;
    unsigned short* dst = Qh + (size_t)b * 1769472 + (size_t)n * 147456
                        + (size_t)(lb + l_loc) * 16 + half;
    *(uint4*)dst = *(const uint4*)&qo[srow * 104 + scol];
  }
  // KV: 1536 chunks: m -> n=m>>7, l_loc=(m&127)>>2, kv=(m>>1)&1, half=m&1
  #pragma unroll
  for (int it = 0; it < 6; it++) {
    int m = tid + it * 256;
    int n = m >> 7, rem = m & 127;
    int l_loc = rem >> 2;
    int kv = (m >> 1) & 1, half = (m & 1) * 8;
    int srow = 2 * l_loc + kv;
    int scol = n * 16 + half;
    unsigned short* dst = KVh + (size_t)b * 3538944 + (size_t)n * 294912
                        + (size_t)(lb + l_loc) * 32 + kv * 16 + half;
    *(uint4*)dst = *(const uint4*)&kvo[srow * 200 + scol];
  }
}

// ---- fused attention + proj: block = 32 pixels x 12 heads, 384 threads ----
// thread = (n = tid>>5, pl = tid&31): per neighbor, each 32-lane group reads
// 32 consecutive 64B pixel blocks -> 2KB contiguous (coalesced by layout).
__global__ __launch_bounds__(384) void attnproj_kernel(
    const unsigned short* __restrict__ Qh, const unsigned short* __restrict__ KVh,
    const unsigned short* __restrict__ wp, const float* __restrict__ bp,
    float* __restrict__ Out)
{
  __shared__ unsigned short s_out[32 * 204];
  const int tid = threadIdx.x;
  const int bl0 = blockIdx.x * 32;

  {
    const int n  = tid >> 5;                   // 0..11
    const int pl = tid & 31;                   // 0..31
    const int bl = bl0 + pl;
    const int l  = bl % LPIX;
    const int b  = bl / LPIX;
    const int h2 = l / HW2, w2 = l - h2 * HW2;

    const unsigned short* qp = Qh + (size_t)b * 1769472 + (size_t)n * 147456
                             + (size_t)l * 16;
    uint4 qA = *(const uint4*)(qp);
    uint4 qB = *(const uint4*)(qp + 8);

    const unsigned short* kvb = KVh + (size_t)b * 3538944 + (size_t)n * 294912;

    int  nbo[9];
    bool okk[9];
    uint4 kA[9], kB[9];
    #pragma unroll
    for (int kk = 0; kk < 9; kk++) {
      int hh = h2 + kk / 3 - 1;
      int ww = w2 + kk % 3 - 1;
      okk[kk] = ((unsigned)hh < (unsigned)HW2) && ((unsigned)ww < (unsigned)HW2);
      int hc = min(max(hh, 0), HW2 - 1);
      int wc = min(max(ww, 0), HW2 - 1);
      nbo[kk] = (hc * HW2 + wc) * 32;
      const unsigned short* kp = kvb + nbo[kk];
      kA[kk] = *(const uint4*)(kp);
      kB[kk] = *(const uint4*)(kp + 8);
    }

    float q[16];
    {
      const unsigned short* qs = (const unsigned short*)&qA;
      #pragma unroll
      for (int j = 0; j < 8; j++) q[j] = bf2f(qs[j]);
      qs = (const unsigned short*)&qB;
      #pragma unroll
      for (int j = 0; j < 8; j++) q[8 + j] = bf2f(qs[j]);
    }

    float sc[9];
    #pragma unroll
    for (int kk = 0; kk < 9; kk++) {
      float s = 0.f;
      const unsigned short* kd = (const unsigned short*)&kA[kk];
      #pragma unroll
      for (int j = 0; j < 8; j++) s = fmaf(q[j], bf2f(kd[j]), s);
      kd = (const unsigned short*)&kB[kk];
      #pragma unroll
      for (int j = 0; j < 8; j++) s = fmaf(q[8 + j], bf2f(kd[j]), s);
      sc[kk] = okk[kk] ? s : 0.f;
    }

    uint4 vA[9], vB[9];
    #pragma unroll
    for (int kk = 0; kk < 9; kk++) {
      const unsigned short* vp = kvb + nbo[kk] + 16;
      vA[kk] = *(const uint4*)(vp);
      vB[kk] = *(const uint4*)(vp + 8);
    }

    float m = sc[0];
    #pragma unroll
    for (int kk = 1; kk < 9; kk++) m = fmaxf(m, sc[kk]);
    float ssum = 0.f;
    #pragma unroll
    for (int kk = 0; kk < 9; kk++) {
      float e = __expf(sc[kk] - m);
      sc[kk] = e;
      ssum += e;
    }

    float acc[16];
    #pragma unroll
    for (int j = 0; j < 16; j++) acc[j] = 0.f;
    #pragma unroll
    for (int kk = 0; kk < 9; kk++) {
      float wgt = okk[kk] ? sc[kk] : 0.f;
      const unsigned short* vd = (const unsigned short*)&vA[kk];
      #pragma unroll
      for (int j = 0; j < 8; j++) acc[j] = fmaf(wgt, bf2f(vd[j]), acc[j]);
      vd = (const unsigned short*)&vB[kk];
      #pragma unroll
      for (int j = 0; j < 8; j++) acc[8 + j] = fmaf(wgt, bf2f(vd[j]), acc[8 + j]);
    }
    float rinv = 1.f / ssum;
    unsigned short od[16];
    #pragma unroll
    for (int j = 0; j < 16; j++) od[j] = f2bf(acc[j] * rinv);
    unsigned short* op = s_out + pl * 204 + n * 16;
    *(uint4*)(op)     = *(uint4*)&od[0];
    *(uint4*)(op + 8) = *(uint4*)&od[8];
  }
  __syncthreads();

  // ---- proj phase: (32x192 bf16 LDS) x Wp^T + bp -> Out fp32, 6 waves ----
  const int lane = tid & 63, w = tid >> 6;     // 6 waves
  const int wr = w & 1, wh = w >> 1;           // wr: row half, wh: 0..2
  const int col  = lane & 15;
  const int koff = (lane >> 4) * 8;
  const int arow = 16 * wr + (lane & 15);
  const int rbase = bl0 + 16 * wr + 4 * (lane >> 4);

  bf16x8 af[6];
  #pragma unroll
  for (int kt = 0; kt < 6; kt++)
    af[kt] = *(const bf16x8*)&s_out[arow * 204 + koff + kt * 32];

  #pragma unroll
  for (int t4 = 0; t4 < 4; t4++) {
    int nt = wh * 4 + t4;
    const unsigned short* wrow = wp + (size_t)(nt * 16 + col) * 192 + koff;
    f32x4 acc = {0.f, 0.f, 0.f, 0.f};
    #pragma unroll
    for (int kt = 0; kt < 6; kt++) {
      bf16x8 bfr = *(const bf16x8*)(wrow + kt * 32);
      acc = __builtin_amdgcn_mfma_f32_16x16x32_bf16(af[kt], bfr, acc, 0, 0, 0);
    }
    int u = nt * 16 + col;
    float bias = bp[u];
    #pragma unroll
    for (int i = 0; i < 4; i++)
      Out[(size_t)(rbase + i) * 192 + u] = acc[i] + bias;
  }
}

extern "C" void kernel_launch(void* const* d_in, const int* in_sizes, int n_in,
                              void* d_out, int out_size, void* d_ws, size_t ws_size,
                              hipStream_t stream) {
  const float* x   = (const float*)d_in[0];
  const float* Wq  = (const float*)d_in[1];
  const float* bq  = (const float*)d_in[2];
  const float* Wkv = (const float*)d_in[3];
  const float* bkv = (const float*)d_in[4];
  const float* Wp  = (const float*)d_in[5];
  const float* bp  = (const float*)d_in[6];
  const float* fqr = (const float*)d_in[7];
  const float* fkr = (const float*)d_in[8];
  const float* fvr = (const float*)d_in[9];

  char* ws = (char*)d_ws;
  unsigned short* Qh   = (unsigned short*)ws;                 // 14,155,776 B
  unsigned short* KVh  = (unsigned short*)(ws + 14155776);    // 28,311,552 B
  unsigned short* wqb  = (unsigned short*)(ws + 42467328);
  unsigned short* wkvb = (unsigned short*)(ws + 42485760);
  unsigned short* wpb  = (unsigned short*)(ws + 42522624);

  cvt_w_kernel<<<dim3(252), dim3(256), 0, stream>>>(Wq, Wkv, Wp, wqb, wkvb, wpb);

  qkv_gemm<<<dim3(1152), dim3(256), 0, stream>>>(
      x, wqb, wkvb, bq, bkv, fqr, fkr, fvr, Qh, KVh);

  attnproj_kernel<<<dim3(1152), dim3(384), 0, stream>>>(
      Qh, KVh, wpb, bp, (float*)d_out);
}

// Round 8
// 73.505 us; speedup vs baseline: 1.2305x; 1.2277x over previous
//
#include <hip/hip_runtime.h>

#define HW2   96
#define NH    12
#define LPIX  (HW2*HW2)      // 9216
#define BATCH 4

typedef __attribute__((ext_vector_type(8))) short bf16x8;
typedef __attribute__((ext_vector_type(4))) float f32x4;

static __device__ __forceinline__ float bf2f(unsigned short u) {
  union { unsigned int i; float f; } v; v.i = ((unsigned int)u) << 16; return v.f;
}
static __device__ __forceinline__ unsigned short f2bf(float f) {
  union { float f; unsigned int i; } v; v.f = f;
  unsigned int r = v.i + 0x7FFF + ((v.i >> 16) & 1);   // round-nearest-even
  return (unsigned short)(r >> 16);
}

// ---- tiny: convert the three weight matrices to bf16 ----------------------
__global__ __launch_bounds__(256) void cvt_w_kernel(
    const float* __restrict__ Wq, const float* __restrict__ Wkv,
    const float* __restrict__ Wp,
    unsigned short* __restrict__ wqb, unsigned short* __restrict__ wkvb,
    unsigned short* __restrict__ wpb) {
  int i = blockIdx.x * 256 + threadIdx.x;
  if (i < 9216)       wqb[i]          = f2bf(Wq[i]);
  else if (i < 27648) wkvb[i - 9216]  = f2bf(Wkv[i - 9216]);
  else if (i < 64512) wpb[i - 27648]  = f2bf(Wp[i - 27648]);
}

// ---- fused Q+KV GEMM (round-5 layout), W loads prefetched in groups -------
__global__ __launch_bounds__(256, 2) void qkv_gemm(
    const float* __restrict__ X,
    const unsigned short* __restrict__ wq, const unsigned short* __restrict__ wkv,
    const float* __restrict__ bq, const float* __restrict__ bkv,
    const float* __restrict__ fqr, const float* __restrict__ fkr,
    const float* __restrict__ fvr,
    unsigned short* __restrict__ Qb, unsigned short* __restrict__ KVb)
{
  __shared__ unsigned short lds[19456];
  unsigned short* xs  = lds;            // stride 120
  unsigned short* qo  = lds;            // stride 104 (64 x 96)
  unsigned short* kvo = lds + 6656;     // stride 200 (64 x 192)

  const int tid = threadIdx.x;
  const int r0  = blockIdx.x * 64;

  const float4* xsrc = (const float4*)(X + (size_t)r0 * 96);
  #pragma unroll
  for (int it = 0; it < 6; it++) {
    int c = tid + it * 256;
    float4 v = xsrc[c];
    int row = c / 24, col = (c % 24) * 4;
    ushort4 p;
    p.x = f2bf(v.x); p.y = f2bf(v.y); p.z = f2bf(v.z); p.w = f2bf(v.w);
    *(ushort4*)&xs[row * 120 + col] = p;
  }
  __syncthreads();

  const int lane = tid & 63, w = tid >> 6;
  const int col  = lane & 15;
  const int koff = (lane >> 4) * 8;
  const int arow = 16 * w + (lane & 15);
  const int rloc = 16 * w + 4 * (lane >> 4);

  bf16x8 af0 = *(const bf16x8*)&xs[arow * 120 + koff];
  bf16x8 af1 = *(const bf16x8*)&xs[arow * 120 + koff + 32];
  bf16x8 af2 = *(const bf16x8*)&xs[arow * 120 + koff + 64];
  __syncthreads();                             // xs dead; reuse as qo/kvo

  const float fqr0 = fqr[0] * 0.07216878364870322f;
  const float fkr0 = fkr[0], fvr0 = fvr[0];

  #pragma unroll
  for (int g = 0; g < 3; g++) {
    // preissue 18 W loads for this group of 6 output tiles
    bf16x8 bw0[6], bw1[6], bw2[6];
    #pragma unroll
    for (int j = 0; j < 6; j++) {
      int nt = g * 6 + j;
      const unsigned short* wrow = (nt < 6)
          ? wq  + (size_t)(nt * 16 + col) * 96 + koff
          : wkv + (size_t)((nt - 6) * 16 + col) * 96 + koff;
      bw0[j] = *(const bf16x8*)(wrow);
      bw1[j] = *(const bf16x8*)(wrow + 32);
      bw2[j] = *(const bf16x8*)(wrow + 64);
    }
    asm volatile("" ::: "memory");             // loads can't sink past here

    #pragma unroll
    for (int j = 0; j < 6; j++) {
      int nt = g * 6 + j;
      f32x4 acc = {0.f, 0.f, 0.f, 0.f};
      acc = __builtin_amdgcn_mfma_f32_16x16x32_bf16(af0, bw0[j], acc, 0, 0, 0);
      acc = __builtin_amdgcn_mfma_f32_16x16x32_bf16(af1, bw1[j], acc, 0, 0, 0);
      acc = __builtin_amdgcn_mfma_f32_16x16x32_bf16(af2, bw2[j], acc, 0, 0, 0);

      if (nt < 6) {
        int u = nt * 16 + col;
        float bias = bq[u];
        #pragma unroll
        for (int i = 0; i < 4; i++)
          qo[(rloc + i) * 104 + u] = f2bf((acc[i] + bias) * fqr0);
      } else {
        int u = (nt - 6) * 16 + col;
        float bias = bkv[u];
        #pragma unroll
        for (int i = 0; i < 4; i++) {
          float s = (i & 1) ? fvr0 : fkr0;     // row parity: even=K, odd=V
          kvo[(rloc + i) * 200 + u] = f2bf((acc[i] + bias) * s);
        }
      }
    }
  }
  __syncthreads();

  #pragma unroll
  for (int it = 0; it < 3; it++) {
    int c = tid + it * 256;
    int row = c / 12, cc = (c % 12) * 8;
    *(bf16x8*)(Qb + (size_t)(r0 + row) * 96 + cc) = *(const bf16x8*)&qo[row * 104 + cc];
  }
  #pragma unroll
  for (int it = 0; it < 6; it++) {
    int c = tid + it * 256;
    int row = c / 24, cc = (c % 24) * 8;
    *(bf16x8*)(KVb + (size_t)(r0 + row) * 192 + cc) = *(const bf16x8*)&kvo[row * 200 + cc];
  }
}

// ---- fused attention + proj: block = 32 pixels x 12 heads, 384 threads ----
// All 36 neighbor K/V loads are issued before a compiler memory fence so
// they stay in flight together (forced memory-level parallelism).
__global__ __launch_bounds__(384, 1) void attnproj_kernel(
    const unsigned short* __restrict__ Qb, const unsigned short* __restrict__ KVb,
    const unsigned short* __restrict__ wp, const float* __restrict__ bp,
    float* __restrict__ Out)
{
  __shared__ unsigned short s_out[32 * 204];
  const int tid = threadIdx.x;
  // XCD-chunked swizzle: 144 consecutive blocks (48 image rows) per XCD,
  // so row+/-1 halo neighbors share an XCD L2.  1152 % 8 == 0 (bijective).
  const int bid = (blockIdx.x & 7) * 144 + (blockIdx.x >> 3);
  const int bl0 = bid * 32;

  {
    const int n  = tid % NH;
    const int pl = tid / NH;                   // 0..31
    const int bl = bl0 + pl;
    const int l  = bl % LPIX;
    const int b  = bl / LPIX;
    const int h2 = l / HW2, w2 = l - h2 * HW2;

    const unsigned short* qp = Qb + (size_t)bl * 192 + n * 16;
    uint4 qA = *(const uint4*)(qp);
    uint4 qB = *(const uint4*)(qp + 8);

    const unsigned short* kvb = KVb + (size_t)b * (LPIX * 384) + n * 16;

    // ---- issue ALL neighbor loads, then fence ----
    int  nbo[9];
    bool okk[9];
    uint4 kA[9], kB[9], vA[9], vB[9];
    #pragma unroll
    for (int kk = 0; kk < 9; kk++) {
      int hh = h2 + kk / 3 - 1;
      int ww = w2 + kk % 3 - 1;
      okk[kk] = ((unsigned)hh < (unsigned)HW2) && ((unsigned)ww < (unsigned)HW2);
      int hc = min(max(hh, 0), HW2 - 1);
      int wc = min(max(ww, 0), HW2 - 1);
      nbo[kk] = (hc * HW2 + wc) * 384;
      const unsigned short* kp = kvb + nbo[kk];
      kA[kk] = *(const uint4*)(kp);
      kB[kk] = *(const uint4*)(kp + 8);
    }
    #pragma unroll
    for (int kk = 0; kk < 9; kk++) {
      const unsigned short* vp = kvb + nbo[kk] + 192;
      vA[kk] = *(const uint4*)(vp);
      vB[kk] = *(const uint4*)(vp + 8);
    }
    asm volatile("" ::: "memory");             // 38 loads in flight here

    float q[16];
    {
      const unsigned short* qs = (const unsigned short*)&qA;
      #pragma unroll
      for (int j = 0; j < 8; j++) q[j] = bf2f(qs[j]);
      qs = (const unsigned short*)&qB;
      #pragma unroll
      for (int j = 0; j < 8; j++) q[8 + j] = bf2f(qs[j]);
    }

    float sc[9];
    #pragma unroll
    for (int kk = 0; kk < 9; kk++) {
      float s = 0.f;
      const unsigned short* kd = (const unsigned short*)&kA[kk];
      #pragma unroll
      for (int j = 0; j < 8; j++) s = fmaf(q[j], bf2f(kd[j]), s);
      kd = (const unsigned short*)&kB[kk];
      #pragma unroll
      for (int j = 0; j < 8; j++) s = fmaf(q[8 + j], bf2f(kd[j]), s);
      sc[kk] = okk[kk] ? s : 0.f;
    }

    float m = sc[0];
    #pragma unroll
    for (int kk = 1; kk < 9; kk++) m = fmaxf(m, sc[kk]);
    float ssum = 0.f;
    #pragma unroll
    for (int kk = 0; kk < 9; kk++) {
      float e = __expf(sc[kk] - m);
      sc[kk] = e;
      ssum += e;
    }

    float acc[16];
    #pragma unroll
    for (int j = 0; j < 16; j++) acc[j] = 0.f;
    #pragma unroll
    for (int kk = 0; kk < 9; kk++) {
      float wgt = okk[kk] ? sc[kk] : 0.f;
      const unsigned short* vd = (const unsigned short*)&vA[kk];
      #pragma unroll
      for (int j = 0; j < 8; j++) acc[j] = fmaf(wgt, bf2f(vd[j]), acc[j]);
      vd = (const unsigned short*)&vB[kk];
      #pragma unroll
      for (int j = 0; j < 8; j++) acc[8 + j] = fmaf(wgt, bf2f(vd[j]), acc[8 + j]);
    }
    float rinv = 1.f / ssum;
    unsigned short od[16];
    #pragma unroll
    for (int j = 0; j < 16; j++) od[j] = f2bf(acc[j] * rinv);
    unsigned short* op = s_out + pl * 204 + n * 16;
    *(uint4*)(op)     = *(uint4*)&od[0];
    *(uint4*)(op + 8) = *(uint4*)&od[8];
  }
  __syncthreads();

  // ---- proj phase: (32x192 bf16 LDS) x Wp^T + bp -> Out fp32, 6 waves ----
  const int lane = tid & 63, w = tid >> 6;     // 6 waves
  const int wr = w & 1, wh = w >> 1;           // wr: row half, wh: 0..2
  const int col  = lane & 15;
  const int koff = (lane >> 4) * 8;
  const int arow = 16 * wr + (lane & 15);
  const int rbase = bl0 + 16 * wr + 4 * (lane >> 4);

  bf16x8 af[6];
  #pragma unroll
  for (int kt = 0; kt < 6; kt++)
    af[kt] = *(const bf16x8*)&s_out[arow * 204 + koff + kt * 32];

  // preissue all 24 W loads for this wave's 4 output tiles
  bf16x8 bw[4][6];
  #pragma unroll
  for (int t4 = 0; t4 < 4; t4++) {
    int nt = wh * 4 + t4;
    const unsigned short* wrow = wp + (size_t)(nt * 16 + col) * 192 + koff;
    #pragma unroll
    for (int kt = 0; kt < 6; kt++)
      bw[t4][kt] = *(const bf16x8*)(wrow + kt * 32);
  }
  asm volatile("" ::: "memory");

  #pragma unroll
  for (int t4 = 0; t4 < 4; t4++) {
    int nt = wh * 4 + t4;
    f32x4 acc = {0.f, 0.f, 0.f, 0.f};
    #pragma unroll
    for (int kt = 0; kt < 6; kt++)
      acc = __builtin_amdgcn_mfma_f32_16x16x32_bf16(af[kt], bw[t4][kt], acc, 0, 0, 0);
    int u = nt * 16 + col;
    float bias = bp[u];
    #pragma unroll
    for (int i = 0; i < 4; i++)
      Out[(size_t)(rbase + i) * 192 + u] = acc[i] + bias;
  }
}

extern "C" void kernel_launch(void* const* d_in, const int* in_sizes, int n_in,
                              void* d_out, int out_size, void* d_ws, size_t ws_size,
                              hipStream_t stream) {
  const float* x   = (const float*)d_in[0];
  const float* Wq  = (const float*)d_in[1];
  const float* bq  = (const float*)d_in[2];
  const float* Wkv = (const float*)d_in[3];
  const float* bkv = (const float*)d_in[4];
  const float* Wp  = (const float*)d_in[5];
  const float* bp  = (const float*)d_in[6];
  const float* fqr = (const float*)d_in[7];
  const float* fkr = (const float*)d_in[8];
  const float* fvr = (const float*)d_in[9];

  char* ws = (char*)d_ws;
  unsigned short* Qb   = (unsigned short*)ws;                 // 14,155,776 B
  unsigned short* KVb  = (unsigned short*)(ws + 14155776);    // 28,311,552 B
  unsigned short* wqb  = (unsigned short*)(ws + 42467328);
  unsigned short* wkvb = (unsigned short*)(ws + 42485760);
  unsigned short* wpb  = (unsigned short*)(ws + 42522624);

  cvt_w_kernel<<<dim3(252), dim3(256), 0, stream>>>(Wq, Wkv, Wp, wqb, wkvb, wpb);

  qkv_gemm<<<dim3(1152), dim3(256), 0, stream>>>(
      x, wqb, wkvb, bq, bkv, fqr, fkr, fvr, Qb, KVb);

  attnproj_kernel<<<dim3(1152), dim3(384), 0, stream>>>(
      Qb, KVb, wpb, bp, (float*)d_out);
}